// Round 2
// baseline (1023.697 us; speedup 1.0000x reference)
//
#include <hip/hip_runtime.h>
#include <hip/hip_bf16.h>
#include <stdint.h>

typedef unsigned short u16;
typedef __attribute__((ext_vector_type(8))) short frag8;   // 8 bf16 (4 VGPRs)
typedef __attribute__((ext_vector_type(4))) float f4;      // 4 f32 acc

#define N8K 8192
#define SK 8    // split-K slices for big GEMM
#define LDA 72  // padded LDS row stride (u16): 144 B = 36 banks -> conflict-free frag reads

__device__ __forceinline__ u16 f2bf(float f) {
  union { float f; unsigned u; } v; v.f = f;
  return (u16)((v.u + 0x7FFFu + ((v.u >> 16) & 1u)) >> 16);   // RNE
}
__device__ __forceinline__ float lrelu(float v) { return v > 0.f ? v : 0.01f * v; }

__device__ __forceinline__ void gld16(const void* g, void* l) {
  __builtin_amdgcn_global_load_lds(
      (__attribute__((address_space(1))) unsigned*)(g),
      (__attribute__((address_space(3))) unsigned*)(l), 16, 0, 0);
}

// ---------------- deg + A_hat(bf16) + dinv ----------------
__global__ __launch_bounds__(256) void k_deg(const int* __restrict__ e,
                                             u16* __restrict__ abf,
                                             float* __restrict__ dinv) {
  int row = blockIdx.x;
  int t = threadIdx.x;
  const int4* er = (const int4*)(e + (size_t)row * N8K);
  ushort4* ar = (ushort4*)(abf + (size_t)row * N8K);
  int cnt = 0;
#pragma unroll
  for (int it = 0; it < 8; ++it) {
    int j4 = it * 256 + t;
    int4 v = er[j4];
    int col = j4 << 2;
    int c0 = (v.x != 0), c1 = (v.y != 0), c2 = (v.z != 0), c3 = (v.w != 0);
    cnt += c0 + c1 + c2 + c3;
    ushort4 a;
    a.x = c0 ? 0x3F80u : 0u;
    a.y = c1 ? 0x3F80u : 0u;
    a.z = c2 ? 0x3F80u : 0u;
    a.w = c3 ? 0x3F80u : 0u;
    if (row >= col && row < col + 4) {          // self-loop
      u16* ap = (u16*)&a;
      int d = row - col;
      ap[d] = ap[d] ? 0x4000u : 0x3F80u;        // 1->2, 0->1 (exact in bf16)
      cnt += 1;
    }
    ar[j4] = a;
  }
#pragma unroll
  for (int o = 32; o > 0; o >>= 1) cnt += __shfl_down(cnt, o);
  __shared__ int part[4];
  if ((t & 63) == 0) part[t >> 6] = cnt;
  __syncthreads();
  if (t == 0) dinv[row] = 1.0f / sqrtf((float)(part[0] + part[1] + part[2] + part[3]));
}

// ---------------- f32 -> bf16 convert ----------------
__global__ __launch_bounds__(256) void k_cvt(const float* __restrict__ x, u16* __restrict__ xb, int n) {
  int i = blockIdx.x * 256 + threadIdx.x;
  if (i < n) xb[i] = f2bf(x[i]);
}

// ---------------- small GEMM: P_t[c][i] = dinv[i] * (X[i][:] . W[:][c]) ----------------
__global__ __launch_bounds__(256) void k_sgemm(const u16* __restrict__ X, int kc, int lkc,
                                               const float* __restrict__ Wa, int wacols,
                                               const float* __restrict__ Wb,
                                               const float* __restrict__ dinv,
                                               u16* __restrict__ Pt) {
  __shared__ __attribute__((aligned(16))) u16 Xs[128 * 128];
  __shared__ __attribute__((aligned(16))) u16 Wt[128 * 128];
  int t = threadIdx.x;
  int mt = blockIdx.x;
  for (int idx = t; idx < (kc << 7); idx += 256) {
    int n = idx >> lkc, k = idx & (kc - 1);
    float v = 0.f;
    if (n < wacols) v = Wa[k * wacols + n];
    else if (Wb)    v = Wb[k * 64 + (n - 64)];
    Wt[(n << lkc) + k] = f2bf(v);
  }
  const u16* gX = X + (size_t)mt * 128 * kc;
  if (kc == 128) {
#pragma unroll
    for (int p = 0; p < 8; ++p) {
      int rr = p * 16 + (t >> 4), sg = t & 15;
      gld16(gX + rr * 128 + sg * 8, Xs + rr * 128 + sg * 8);
    }
  } else {
#pragma unroll
    for (int p = 0; p < 4; ++p) {
      int rr = p * 32 + (t >> 3), sg = t & 7;
      gld16(gX + rr * 64 + sg * 8, Xs + rr * 64 + sg * 8);
    }
  }
  __syncthreads();
  int wave = t >> 6, lane = t & 63;
  int wm = (wave >> 1) * 64, wn = (wave & 1) * 64;
  int fm = lane & 15, fk = (lane >> 4) * 8;
  f4 acc[4][4];
#pragma unroll
  for (int m = 0; m < 4; ++m)
#pragma unroll
    for (int n = 0; n < 4; ++n) acc[m][n] = (f4){0.f, 0.f, 0.f, 0.f};
  for (int ki = 0; ki < kc; ki += 32) {
    frag8 a[4], b[4];
#pragma unroll
    for (int m = 0; m < 4; ++m) a[m] = *(const frag8*)&Xs[(wm + 16 * m + fm) * kc + ki + fk];
#pragma unroll
    for (int n = 0; n < 4; ++n) b[n] = *(const frag8*)&Wt[((wn + 16 * n + fm) << lkc) + ki + fk];
#pragma unroll
    for (int m = 0; m < 4; ++m)
#pragma unroll
      for (int n = 0; n < 4; ++n)
        acc[m][n] = __builtin_amdgcn_mfma_f32_16x16x32_bf16(a[m], b[n], acc[m][n], 0, 0, 0);
  }
  int rbase = (lane >> 4) * 4;
#pragma unroll
  for (int m = 0; m < 4; ++m) {
    int i0 = mt * 128 + wm + 16 * m + rbase;
    float d0 = dinv[i0], d1 = dinv[i0 + 1], d2 = dinv[i0 + 2], d3 = dinv[i0 + 3];
#pragma unroll
    for (int n = 0; n < 4; ++n) {
      int c = wn + 16 * n + fm;
      ushort4 o;
      o.x = f2bf(d0 * acc[m][n][0]);
      o.y = f2bf(d1 * acc[m][n][1]);
      o.z = f2bf(d2 * acc[m][n][2]);
      o.w = f2bf(d3 * acc[m][n][3]);
      *(ushort4*)&Pt[(size_t)c * N8K + i0] = o;   // P stored transposed [c][i]
    }
  }
}

// ---------------- big GEMM (split-K): Ctmp[ks] = A_hat @ P ----------------
// VGPR staging + padded LDS (stride 72 u16) -> conflict-free ds_write_b128 / ds_read_b128.
// Next K-tile global loads issued right after barrier-2: overlap compute, drain at next barrier.
__global__ __launch_bounds__(256) void k_bgemm(const u16* __restrict__ A,
                                               const u16* __restrict__ Pt,
                                               float* __restrict__ Ctmp) {
  __shared__ __attribute__((aligned(16))) u16 As[128 * LDA];
  __shared__ __attribute__((aligned(16))) u16 Bs[128 * LDA];
  int t = threadIdx.x;
  int mt = blockIdx.x, ks = blockIdx.y;
  const int KS = N8K / SK;
  int wave = t >> 6, lane = t & 63;
  int wm = (wave >> 1) * 64, wn = (wave & 1) * 64;
  int fm = lane & 15, fk = (lane >> 4) * 8;
  f4 acc[4][4];
#pragma unroll
  for (int m = 0; m < 4; ++m)
#pragma unroll
    for (int n = 0; n < 4; ++n) acc[m][n] = (f4){0.f, 0.f, 0.f, 0.f};

  int arow = t >> 3, aseg = t & 7;                 // 32 rows x 8 segs per pass
  const u16* gA0 = A + (size_t)(mt * 128 + arow) * N8K + aseg * 8;
  const u16* gB0 = Pt + (size_t)arow * N8K + aseg * 8;
  u16* lA = As + arow * LDA + aseg * 8;
  u16* lB = Bs + arow * LDA + aseg * 8;

  int4 ra[4], rb[4];
  int k0 = ks * KS, k1 = ks * KS + KS;
#pragma unroll
  for (int p = 0; p < 4; ++p) {
    ra[p] = *(const int4*)(gA0 + (size_t)p * 32 * N8K + k0);
    rb[p] = *(const int4*)(gB0 + (size_t)p * 32 * N8K + k0);
  }
  for (int kk = k0; kk < k1; kk += 64) {
    __syncthreads();
#pragma unroll
    for (int p = 0; p < 4; ++p) {
      *(int4*)(lA + p * 32 * LDA) = ra[p];
      *(int4*)(lB + p * 32 * LDA) = rb[p];
    }
    __syncthreads();
    if (kk + 64 < k1) {
#pragma unroll
      for (int p = 0; p < 4; ++p) {                // prefetch next tile (overlaps MFMA)
        ra[p] = *(const int4*)(gA0 + (size_t)p * 32 * N8K + kk + 64);
        rb[p] = *(const int4*)(gB0 + (size_t)p * 32 * N8K + kk + 64);
      }
    }
#pragma unroll
    for (int ki = 0; ki < 64; ki += 32) {
      frag8 a[4], b[4];
#pragma unroll
      for (int m = 0; m < 4; ++m) a[m] = *(const frag8*)&As[(wm + 16 * m + fm) * LDA + ki + fk];
#pragma unroll
      for (int n = 0; n < 4; ++n) b[n] = *(const frag8*)&Bs[(wn + 16 * n + fm) * LDA + ki + fk];
#pragma unroll
      for (int m = 0; m < 4; ++m)
#pragma unroll
        for (int n = 0; n < 4; ++n)
          acc[m][n] = __builtin_amdgcn_mfma_f32_16x16x32_bf16(a[m], b[n], acc[m][n], 0, 0, 0);
    }
  }
  float* Co = Ctmp + (size_t)ks * N8K * 128;
  int rbase = (lane >> 4) * 4;
#pragma unroll
  for (int m = 0; m < 4; ++m) {
    int i0 = mt * 128 + wm + 16 * m + rbase;
#pragma unroll
    for (int n = 0; n < 4; ++n) {
      int c = wn + 16 * n + fm;
#pragma unroll
      for (int r = 0; r < 4; ++r) Co[(size_t)(i0 + r) * 128 + c] = acc[m][n][r];
    }
  }
}

// ---------------- epilogue ----------------
__global__ __launch_bounds__(256) void k_epi(const float* __restrict__ Ctmp, const float* __restrict__ dinv,
                                             const float* __restrict__ bA, const float* __restrict__ bB,
                                             float* __restrict__ outF, u16* __restrict__ oB1,
                                             u16* __restrict__ oB2, int mode) {
  int idx = blockIdx.x * 256 + threadIdx.x;
  int i = idx >> 7, c = idx & 127;
  float s = 0.f;
#pragma unroll
  for (int k = 0; k < SK; ++k) s += Ctmp[(size_t)k * 1048576 + idx];
  if (mode == 1) {
    if (c < 64) oB1[i * 64 + c] = f2bf(lrelu(dinv[i] * s + bA[c]));
  } else if (mode == 2) {
    float v = lrelu(dinv[i] * s + bA[c]);
    outF[idx] = v;
    oB1[idx] = f2bf(v);
  } else if (mode == 3) {
    if (c < 64) oB1[i * 64 + c] = f2bf(lrelu(dinv[i] * s + bA[c]));
    else        oB2[i * 64 + (c - 64)] = f2bf(lrelu(dinv[i] * s + bB[c - 64]));
  } else {
    outF[idx] = lrelu(dinv[i] * s + bA[c]);
  }
}

// ---------------- recon = sigmoid(re @ re^T) ----------------
// Epilogue transposes 32-row chunks through padded LDS -> 512B-contiguous float4 row stores.
__global__ __launch_bounds__(256) void k_recon(const u16* __restrict__ re, float* __restrict__ out) {
  __shared__ __attribute__((aligned(16))) u16 Ra[128 * 64];
  __shared__ __attribute__((aligned(16))) u16 Rb[128 * 64];
  __shared__ __attribute__((aligned(16))) float Ls[32 * 132];
  int t = threadIdx.x;
  int bi = blockIdx.x, bj = blockIdx.y;
  int r0 = t >> 3, sg = t & 7;
#pragma unroll
  for (int p = 0; p < 4; ++p) {
    int rr = p * 32 + r0;
    gld16(re + (size_t)(bi * 128 + rr) * 64 + sg * 8, Ra + rr * 64 + sg * 8);
    gld16(re + (size_t)(bj * 128 + rr) * 64 + sg * 8, Rb + rr * 64 + sg * 8);
  }
  __syncthreads();
  int wave = t >> 6, lane = t & 63;
  int wm = (wave >> 1) * 64, wn = (wave & 1) * 64;
  int fm = lane & 15, fk = (lane >> 4) * 8;
  f4 acc[4][4];
#pragma unroll
  for (int m = 0; m < 4; ++m)
#pragma unroll
    for (int n = 0; n < 4; ++n) acc[m][n] = (f4){0.f, 0.f, 0.f, 0.f};
#pragma unroll
  for (int ki = 0; ki < 64; ki += 32) {
    frag8 a[4], b[4];
#pragma unroll
    for (int m = 0; m < 4; ++m) a[m] = *(const frag8*)&Ra[(wm + 16 * m + fm) * 64 + ki + fk];
#pragma unroll
    for (int n = 0; n < 4; ++n) b[n] = *(const frag8*)&Rb[(wn + 16 * n + fm) * 64 + ki + fk];
#pragma unroll
    for (int m = 0; m < 4; ++m)
#pragma unroll
      for (int n = 0; n < 4; ++n)
        acc[m][n] = __builtin_amdgcn_mfma_f32_16x16x32_bf16(a[m], b[n], acc[m][n], 0, 0, 0);
  }
  int rbase = (lane >> 4) * 4;
#pragma unroll
  for (int chunk = 0; chunk < 4; ++chunk) {
    __syncthreads();
    if (wm == (chunk >> 1) * 64) {
      int mlo = (chunk & 1) * 2;
#pragma unroll
      for (int mm = 0; mm < 2; ++mm) {
        int m = mlo + mm;
        int lrow = (16 * m + rbase) & 31;
#pragma unroll
        for (int n = 0; n < 4; ++n) {
          int col = wn + 16 * n + fm;
#pragma unroll
          for (int r = 0; r < 4; ++r)
            Ls[(lrow + r) * 132 + col] = 1.0f / (1.0f + __expf(-acc[m][n][r]));
        }
      }
    }
    __syncthreads();
#pragma unroll
    for (int it = 0; it < 4; ++it) {
      int lr = it * 8 + (t >> 5);
      int col = (t & 31) * 4;
      float4 v = *(const float4*)&Ls[lr * 132 + col];
      *(float4*)&out[(size_t)(bi * 128 + chunk * 32 + lr) * N8K + bj * 128 + col] = v;
    }
  }
}

extern "C" void kernel_launch(void* const* d_in, const int* in_sizes, int n_in,
                              void* d_out, int out_size, void* d_ws, size_t ws_size,
                              hipStream_t stream) {
  const float* x   = (const float*)d_in[0];
  const int*   e   = (const int*)d_in[1];
  const float* W1  = (const float*)d_in[2];
  const float* b1  = (const float*)d_in[3];
  const float* W2  = (const float*)d_in[4];
  const float* b2  = (const float*)d_in[5];
  const float* We  = (const float*)d_in[6];
  const float* be  = (const float*)d_in[7];
  const float* Wd1 = (const float*)d_in[8];
  const float* bd1 = (const float*)d_in[9];
  const float* Wd2 = (const float*)d_in[10];
  const float* bd2 = (const float*)d_in[11];

  float* out       = (float*)d_out;
  float* out_recon = out;                         // [8192*8192]
  float* out_x     = out + 67108864;              // [8192*128]
  float* out_z     = out + 67108864 + 1048576;    // [8192*128]

  // Big scratch aliased into the recon region of d_out (overwritten only by k_recon last):
  u16*   abf  = (u16*)d_out;                      // A_hat bf16: 128 MB
  float* Ctmp = out + 33554432;                   // split-K partials: 32 MB

  char* ws = (char*)d_ws;
  float* dinv = (float*)(ws);
  u16* Pt   = (u16*)(ws + 32768);
  u16* xbf  = (u16*)(ws + 32768 + 2097152);
  u16* hbf  = (u16*)(ws + 32768 + 2097152 + 2097152);
  u16* zbf  = (u16*)(ws + 32768 + 2097152 + 2097152 + 1048576);
  u16* rebf = (u16*)(ws + 32768 + 2097152 + 2097152 + 1048576 + 2097152);
  u16* xdbf = (u16*)(ws + 32768 + 2097152 + 2097152 + 1048576 + 2097152 + 1048576);

  k_deg<<<8192, 256, 0, stream>>>(e, abf, dinv);
  k_cvt<<<4096, 256, 0, stream>>>(x, xbf, 1048576);

  // stage 1: h
  k_sgemm<<<64, 256, 0, stream>>>(xbf, 128, 7, W1, 64, nullptr, dinv, Pt);
  k_bgemm<<<dim3(64, SK), 256, 0, stream>>>(abf, Pt, Ctmp);
  k_epi<<<4096, 256, 0, stream>>>(Ctmp, dinv, b1, nullptr, nullptr, hbf, nullptr, 1);

  // stage 2: z
  k_sgemm<<<64, 256, 0, stream>>>(hbf, 64, 6, W2, 128, nullptr, dinv, Pt);
  k_bgemm<<<dim3(64, SK), 256, 0, stream>>>(abf, Pt, Ctmp);
  k_epi<<<4096, 256, 0, stream>>>(Ctmp, dinv, b2, nullptr, out_z, zbf, nullptr, 2);

  // stage 3: [re | xd]
  k_sgemm<<<64, 256, 0, stream>>>(zbf, 128, 7, We, 64, Wd1, dinv, Pt);
  k_bgemm<<<dim3(64, SK), 256, 0, stream>>>(abf, Pt, Ctmp);
  k_epi<<<4096, 256, 0, stream>>>(Ctmp, dinv, be, bd1, nullptr, rebf, xdbf, 3);

  // stage 4: x_out
  k_sgemm<<<64, 256, 0, stream>>>(xdbf, 64, 6, Wd2, 128, nullptr, dinv, Pt);
  k_bgemm<<<dim3(64, SK), 256, 0, stream>>>(abf, Pt, Ctmp);
  k_epi<<<4096, 256, 0, stream>>>(Ctmp, dinv, bd2, nullptr, out_x, nullptr, nullptr, 4);

  // recon = sigmoid(re @ re^T)
  k_recon<<<dim3(64, 64), 256, 0, stream>>>(rebf, out_recon);
}

// Round 3
// 850.051 us; speedup vs baseline: 1.2043x; 1.2043x over previous
//
#include <hip/hip_runtime.h>
#include <hip/hip_bf16.h>
#include <stdint.h>

typedef unsigned short u16;
typedef unsigned char u8;
typedef unsigned int u32;
typedef __attribute__((ext_vector_type(8))) short frag8;   // 8 bf16 (4 VGPRs)
typedef __attribute__((ext_vector_type(4))) float f4;      // 4 f32 acc

#define N8K 8192
#define SK 8    // split-K slices for big GEMM

__device__ __forceinline__ u16 f2bf(float f) {
  union { float f; unsigned u; } v; v.f = f;
  return (u16)((v.u + 0x7FFFu + ((v.u >> 16) & 1u)) >> 16);   // RNE
}
__device__ __forceinline__ float lrelu(float v) { return v > 0.f ? v : 0.01f * v; }

__device__ __forceinline__ void gld16(const void* g, void* l) {
  __builtin_amdgcn_global_load_lds(
      (__attribute__((address_space(1))) unsigned*)(g),
      (__attribute__((address_space(3))) unsigned*)(l), 16, 0, 0);
}

// expand 4 A-codes (bytes in w, values 0/1/2) -> 2 dwords = 4 bf16 {0,1,2}
// LUT via v_perm: hi byte {00,3F,40}, lo byte {00,80,00}
__device__ __forceinline__ void expand4(u32 w, u32& o0, u32& o1) {
  u32 hi = __builtin_amdgcn_perm(0u, 0x00403F00u, w);   // sel<4 -> S1 byte
  u32 lo = __builtin_amdgcn_perm(0u, 0x00008000u, w);
  o0 = __builtin_amdgcn_perm(hi, lo, 0x05010400u);      // [lo0,hi0,lo1,hi1]
  o1 = __builtin_amdgcn_perm(hi, lo, 0x07030602u);      // [lo2,hi2,lo3,hi3]
}

// ---------------- deg + A_hat(byte codes) + dinv ----------------
__global__ __launch_bounds__(256) void k_deg(const int* __restrict__ e,
                                             u8* __restrict__ ab,
                                             float* __restrict__ dinv) {
  int row = blockIdx.x;
  int t = threadIdx.x;
  const int4* er = (const int4*)(e + (size_t)row * N8K);
  u32* ar = (u32*)(ab + (size_t)row * N8K);
  int cnt = 0;
#pragma unroll
  for (int it = 0; it < 8; ++it) {
    int j4 = it * 256 + t;
    int4 v = er[j4];
    int col = j4 << 2;
    u32 c0 = (v.x != 0), c1 = (v.y != 0), c2 = (v.z != 0), c3 = (v.w != 0);
    cnt += (int)(c0 + c1 + c2 + c3);
    u32 w = c0 | (c1 << 8) | (c2 << 16) | (c3 << 24);
    if (row >= col && row < col + 4) {          // self-loop: code += 1 on diagonal
      w += 1u << (8 * (row - col));             // 0->1, 1->2 (no byte carry possible)
      cnt += 1;
    }
    ar[j4] = w;
  }
#pragma unroll
  for (int o = 32; o > 0; o >>= 1) cnt += __shfl_down(cnt, o);
  __shared__ int part[4];
  if ((t & 63) == 0) part[t >> 6] = cnt;
  __syncthreads();
  if (t == 0) dinv[row] = 1.0f / sqrtf((float)(part[0] + part[1] + part[2] + part[3]));
}

// ---------------- f32 -> bf16 convert ----------------
__global__ __launch_bounds__(256) void k_cvt(const float* __restrict__ x, u16* __restrict__ xb, int n) {
  int i = blockIdx.x * 256 + threadIdx.x;
  if (i < n) xb[i] = f2bf(x[i]);
}

// ---------------- small GEMM: P_t[c][i] = dinv[i] * (X[i][:] . W[:][c]) ----------------
__global__ __launch_bounds__(256) void k_sgemm(const u16* __restrict__ X, int kc, int lkc,
                                               const float* __restrict__ Wa, int wacols,
                                               const float* __restrict__ Wb,
                                               const float* __restrict__ dinv,
                                               u16* __restrict__ Pt) {
  __shared__ __attribute__((aligned(16))) u16 Xs[128 * 128];
  __shared__ __attribute__((aligned(16))) u16 Wt[128 * 128];
  int t = threadIdx.x;
  int mt = blockIdx.x;
  for (int idx = t; idx < (kc << 7); idx += 256) {
    int n = idx >> lkc, k = idx & (kc - 1);
    float v = 0.f;
    if (n < wacols) v = Wa[k * wacols + n];
    else if (Wb)    v = Wb[k * 64 + (n - 64)];
    Wt[(n << lkc) + k] = f2bf(v);
  }
  const u16* gX = X + (size_t)mt * 128 * kc;
  if (kc == 128) {
#pragma unroll
    for (int p = 0; p < 8; ++p) {
      int rr = p * 16 + (t >> 4), sg = t & 15;
      gld16(gX + rr * 128 + sg * 8, Xs + rr * 128 + sg * 8);
    }
  } else {
#pragma unroll
    for (int p = 0; p < 4; ++p) {
      int rr = p * 32 + (t >> 3), sg = t & 7;
      gld16(gX + rr * 64 + sg * 8, Xs + rr * 64 + sg * 8);
    }
  }
  __syncthreads();
  int wave = t >> 6, lane = t & 63;
  int wm = (wave >> 1) * 64, wn = (wave & 1) * 64;
  int fm = lane & 15, fk = (lane >> 4) * 8;
  f4 acc[4][4];
#pragma unroll
  for (int m = 0; m < 4; ++m)
#pragma unroll
    for (int n = 0; n < 4; ++n) acc[m][n] = (f4){0.f, 0.f, 0.f, 0.f};
  for (int ki = 0; ki < kc; ki += 32) {
    frag8 a[4], b[4];
#pragma unroll
    for (int m = 0; m < 4; ++m) a[m] = *(const frag8*)&Xs[(wm + 16 * m + fm) * kc + ki + fk];
#pragma unroll
    for (int n = 0; n < 4; ++n) b[n] = *(const frag8*)&Wt[((wn + 16 * n + fm) << lkc) + ki + fk];
#pragma unroll
    for (int m = 0; m < 4; ++m)
#pragma unroll
      for (int n = 0; n < 4; ++n)
        acc[m][n] = __builtin_amdgcn_mfma_f32_16x16x32_bf16(a[m], b[n], acc[m][n], 0, 0, 0);
  }
  int rbase = (lane >> 4) * 4;
#pragma unroll
  for (int m = 0; m < 4; ++m) {
    int i0 = mt * 128 + wm + 16 * m + rbase;
    float d0 = dinv[i0], d1 = dinv[i0 + 1], d2 = dinv[i0 + 2], d3 = dinv[i0 + 3];
#pragma unroll
    for (int n = 0; n < 4; ++n) {
      int c = wn + 16 * n + fm;
      ushort4 o;
      o.x = f2bf(d0 * acc[m][n][0]);
      o.y = f2bf(d1 * acc[m][n][1]);
      o.z = f2bf(d2 * acc[m][n][2]);
      o.w = f2bf(d3 * acc[m][n][3]);
      *(ushort4*)&Pt[(size_t)c * N8K + i0] = o;   // P stored transposed [c][i]
    }
  }
}

// ---------------- big GEMM (split-K): Ctmp[ks] = A_hat @ P ----------------
// LDS-free: MFMA fragments loaded straight global->VGPR (A as byte codes,
// expanded in-register via v_perm LUT; B rows from Pt, L2/L3-resident).
// No barriers in the K-loop; L1 absorbs the 2x intra-block row reuse.
__global__ __launch_bounds__(256) void k_bgemm(const u8* __restrict__ Ab,
                                               const u16* __restrict__ Pt,
                                               float* __restrict__ Ctmp) {
  int t = threadIdx.x;
  int mt = blockIdx.x, ks = blockIdx.y;
  const int KS = N8K / SK;
  int wave = t >> 6, lane = t & 63;
  int wm = (wave >> 1) * 64, wn = (wave & 1) * 64;
  int fm = lane & 15, fk = (lane >> 4) * 8;
  f4 acc[4][4];
#pragma unroll
  for (int m = 0; m < 4; ++m)
#pragma unroll
    for (int n = 0; n < 4; ++n) acc[m][n] = (f4){0.f, 0.f, 0.f, 0.f};

  const u8* pa0 = Ab + (size_t)(mt * 128 + wm + fm) * N8K + ks * KS + fk;
  const u16* pb0 = Pt + (size_t)(wn + fm) * N8K + ks * KS + fk;

#pragma unroll 2
  for (int kk = 0; kk < KS; kk += 32) {
    frag8 a[4], b[4];
#pragma unroll
    for (int m = 0; m < 4; ++m) {
      uint2 w = *(const uint2*)(pa0 + (size_t)(16 * m) * N8K + kk);
      uint4 r;
      expand4(w.x, r.x, r.y);
      expand4(w.y, r.z, r.w);
      a[m] = *(frag8*)&r;
    }
#pragma unroll
    for (int n = 0; n < 4; ++n)
      b[n] = *(const frag8*)(pb0 + (size_t)(16 * n) * N8K + kk);
#pragma unroll
    for (int m = 0; m < 4; ++m)
#pragma unroll
      for (int n = 0; n < 4; ++n)
        acc[m][n] = __builtin_amdgcn_mfma_f32_16x16x32_bf16(a[m], b[n], acc[m][n], 0, 0, 0);
  }

  float* Co = Ctmp + (size_t)ks * N8K * 128;
  int rbase = (lane >> 4) * 4;
#pragma unroll
  for (int m = 0; m < 4; ++m) {
    int i0 = mt * 128 + wm + 16 * m + rbase;
#pragma unroll
    for (int n = 0; n < 4; ++n) {
      int c = wn + 16 * n + fm;
#pragma unroll
      for (int r = 0; r < 4; ++r) Co[(size_t)(i0 + r) * 128 + c] = acc[m][n][r];
    }
  }
}

// ---------------- epilogue: sum split-K, dinv scale, +bias, lrelu, scatter ----------------
__global__ __launch_bounds__(256) void k_epi(const float* __restrict__ Ctmp, const float* __restrict__ dinv,
                                             const float* __restrict__ bA, const float* __restrict__ bB,
                                             float* __restrict__ outF, u16* __restrict__ oB1,
                                             u16* __restrict__ oB2, int mode) {
  int idx = blockIdx.x * 256 + threadIdx.x;
  int i = idx >> 7, c = idx & 127;
  float s = 0.f;
#pragma unroll
  for (int k = 0; k < SK; ++k) s += Ctmp[(size_t)k * 1048576 + idx];
  if (mode == 1) {
    if (c < 64) oB1[i * 64 + c] = f2bf(lrelu(dinv[i] * s + bA[c]));
  } else if (mode == 2) {
    float v = lrelu(dinv[i] * s + bA[c]);
    outF[idx] = v;
    oB1[idx] = f2bf(v);
  } else if (mode == 3) {
    if (c < 64) oB1[i * 64 + c] = f2bf(lrelu(dinv[i] * s + bA[c]));
    else        oB2[i * 64 + (c - 64)] = f2bf(lrelu(dinv[i] * s + bB[c - 64]));
  } else {
    outF[idx] = lrelu(dinv[i] * s + bA[c]);
  }
}

// ---------------- recon = sigmoid(re @ re^T) ----------------
// LDS-free fragments (re is 1 MB, L2-resident); round-1 direct stores.
__global__ __launch_bounds__(256) void k_recon(const u16* __restrict__ re, float* __restrict__ out) {
  int t = threadIdx.x;
  int bi = blockIdx.x, bj = blockIdx.y;
  int wave = t >> 6, lane = t & 63;
  int wm = (wave >> 1) * 64, wn = (wave & 1) * 64;
  int fm = lane & 15, fk = (lane >> 4) * 8;
  const u16* pa0 = re + (size_t)(bi * 128 + wm + fm) * 64 + fk;
  const u16* pb0 = re + (size_t)(bj * 128 + wn + fm) * 64 + fk;
  f4 acc[4][4];
#pragma unroll
  for (int m = 0; m < 4; ++m)
#pragma unroll
    for (int n = 0; n < 4; ++n) acc[m][n] = (f4){0.f, 0.f, 0.f, 0.f};
#pragma unroll
  for (int ki = 0; ki < 64; ki += 32) {
    frag8 a[4], b[4];
#pragma unroll
    for (int m = 0; m < 4; ++m) a[m] = *(const frag8*)(pa0 + (size_t)(16 * m) * 64 + ki);
#pragma unroll
    for (int n = 0; n < 4; ++n) b[n] = *(const frag8*)(pb0 + (size_t)(16 * n) * 64 + ki);
#pragma unroll
    for (int m = 0; m < 4; ++m)
#pragma unroll
      for (int n = 0; n < 4; ++n)
        acc[m][n] = __builtin_amdgcn_mfma_f32_16x16x32_bf16(a[m], b[n], acc[m][n], 0, 0, 0);
  }
  int rbase = (lane >> 4) * 4;
#pragma unroll
  for (int m = 0; m < 4; ++m) {
#pragma unroll
    for (int n = 0; n < 4; ++n) {
      int gj = bj * 128 + wn + 16 * n + fm;
#pragma unroll
      for (int r = 0; r < 4; ++r) {
        int gi = bi * 128 + wm + 16 * m + rbase + r;
        float v = acc[m][n][r];
        out[(size_t)gi * N8K + gj] = 1.0f / (1.0f + __expf(-v));
      }
    }
  }
}

extern "C" void kernel_launch(void* const* d_in, const int* in_sizes, int n_in,
                              void* d_out, int out_size, void* d_ws, size_t ws_size,
                              hipStream_t stream) {
  const float* x   = (const float*)d_in[0];
  const int*   e   = (const int*)d_in[1];
  const float* W1  = (const float*)d_in[2];
  const float* b1  = (const float*)d_in[3];
  const float* W2  = (const float*)d_in[4];
  const float* b2  = (const float*)d_in[5];
  const float* We  = (const float*)d_in[6];
  const float* be  = (const float*)d_in[7];
  const float* Wd1 = (const float*)d_in[8];
  const float* bd1 = (const float*)d_in[9];
  const float* Wd2 = (const float*)d_in[10];
  const float* bd2 = (const float*)d_in[11];

  float* out       = (float*)d_out;
  float* out_recon = out;                         // [8192*8192]
  float* out_x     = out + 67108864;              // [8192*128]
  float* out_z     = out + 67108864 + 1048576;    // [8192*128]

  // Scratch aliased into the recon region of d_out (overwritten only by k_recon last):
  u8*    abyte = (u8*)d_out;                      // A_hat codes: 64 MB at [0,64M)
  float* Ctmp  = out + 16777216;                  // split-K partials: 32 MB at [64M,96M)

  char* ws = (char*)d_ws;
  float* dinv = (float*)(ws);
  u16* Pt   = (u16*)(ws + 32768);
  u16* xbf  = (u16*)(ws + 32768 + 2097152);
  u16* hbf  = (u16*)(ws + 32768 + 2097152 + 2097152);
  u16* zbf  = (u16*)(ws + 32768 + 2097152 + 2097152 + 1048576);
  u16* rebf = (u16*)(ws + 32768 + 2097152 + 2097152 + 1048576 + 2097152);
  u16* xdbf = (u16*)(ws + 32768 + 2097152 + 2097152 + 1048576 + 2097152 + 1048576);

  k_deg<<<8192, 256, 0, stream>>>(e, abyte, dinv);
  k_cvt<<<4096, 256, 0, stream>>>(x, xbf, 1048576);

  // stage 1: h
  k_sgemm<<<64, 256, 0, stream>>>(xbf, 128, 7, W1, 64, nullptr, dinv, Pt);
  k_bgemm<<<dim3(64, SK), 256, 0, stream>>>(abyte, Pt, Ctmp);
  k_epi<<<4096, 256, 0, stream>>>(Ctmp, dinv, b1, nullptr, nullptr, hbf, nullptr, 1);

  // stage 2: z
  k_sgemm<<<64, 256, 0, stream>>>(hbf, 64, 6, W2, 128, nullptr, dinv, Pt);
  k_bgemm<<<dim3(64, SK), 256, 0, stream>>>(abyte, Pt, Ctmp);
  k_epi<<<4096, 256, 0, stream>>>(Ctmp, dinv, b2, nullptr, out_z, zbf, nullptr, 2);

  // stage 3: [re | xd] in one GEMM via [We | Wd1]
  k_sgemm<<<64, 256, 0, stream>>>(zbf, 128, 7, We, 64, Wd1, dinv, Pt);
  k_bgemm<<<dim3(64, SK), 256, 0, stream>>>(abyte, Pt, Ctmp);
  k_epi<<<4096, 256, 0, stream>>>(Ctmp, dinv, be, bd1, nullptr, rebf, xdbf, 3);

  // stage 4: x_out
  k_sgemm<<<64, 256, 0, stream>>>(xdbf, 64, 6, Wd2, 128, nullptr, dinv, Pt);
  k_bgemm<<<dim3(64, SK), 256, 0, stream>>>(abyte, Pt, Ctmp);
  k_epi<<<4096, 256, 0, stream>>>(Ctmp, dinv, bd2, nullptr, out_x, nullptr, nullptr, 4);

  // recon = sigmoid(re @ re^T) — overwrites the abyte/Ctmp scratch region last
  k_recon<<<dim3(64, 64), 256, 0, stream>>>(rebf, out_recon);
}

// Round 4
// 711.801 us; speedup vs baseline: 1.4382x; 1.1942x over previous
//
#include <hip/hip_runtime.h>
#include <hip/hip_bf16.h>
#include <stdint.h>

typedef unsigned short u16;
typedef unsigned char u8;
typedef unsigned int u32;
typedef __attribute__((ext_vector_type(8))) short frag8;   // 8 bf16 (4 VGPRs)
typedef __attribute__((ext_vector_type(4))) float f4;      // 4 f32 acc

#define N8K 8192
#define SK 8    // split-K slices for big GEMM

__device__ __forceinline__ u16 f2bf(float f) {
  union { float f; unsigned u; } v; v.f = f;
  return (u16)((v.u + 0x7FFFu + ((v.u >> 16) & 1u)) >> 16);   // RNE
}
__device__ __forceinline__ float lrelu(float v) { return v > 0.f ? v : 0.01f * v; }

__device__ __forceinline__ void gld16(const void* g, void* l) {
  __builtin_amdgcn_global_load_lds(
      (__attribute__((address_space(1))) unsigned*)(g),
      (__attribute__((address_space(3))) unsigned*)(l), 16, 0, 0);
}

// expand 4 A-codes (bytes in w, values 0/1/2) -> 2 dwords = 4 bf16 {0,1,2}
__device__ __forceinline__ void expand4(u32 w, u32& o0, u32& o1) {
  u32 hi = __builtin_amdgcn_perm(0u, 0x00403F00u, w);
  u32 lo = __builtin_amdgcn_perm(0u, 0x00008000u, w);
  o0 = __builtin_amdgcn_perm(hi, lo, 0x05010400u);      // [lo0,hi0,lo1,hi1]
  o1 = __builtin_amdgcn_perm(hi, lo, 0x07030602u);      // [lo2,hi2,lo3,hi3]
}

// ---------------- deg + A_hat(byte codes) + dinv ----------------
__global__ __launch_bounds__(256) void k_deg(const int* __restrict__ e,
                                             u8* __restrict__ ab,
                                             float* __restrict__ dinv) {
  int row = blockIdx.x;
  int t = threadIdx.x;
  const int4* er = (const int4*)(e + (size_t)row * N8K);
  u32* ar = (u32*)(ab + (size_t)row * N8K);
  int cnt = 0;
#pragma unroll
  for (int it = 0; it < 8; ++it) {
    int j4 = it * 256 + t;
    int4 v = er[j4];
    int col = j4 << 2;
    u32 c0 = (v.x != 0), c1 = (v.y != 0), c2 = (v.z != 0), c3 = (v.w != 0);
    cnt += (int)(c0 + c1 + c2 + c3);
    u32 w = c0 | (c1 << 8) | (c2 << 16) | (c3 << 24);
    if (row >= col && row < col + 4) {          // self-loop: code += 1 on diagonal
      w += 1u << (8 * (row - col));
      cnt += 1;
    }
    ar[j4] = w;
  }
#pragma unroll
  for (int o = 32; o > 0; o >>= 1) cnt += __shfl_down(cnt, o);
  __shared__ int part[4];
  if ((t & 63) == 0) part[t >> 6] = cnt;
  __syncthreads();
  if (t == 0) dinv[row] = 1.0f / sqrtf((float)(part[0] + part[1] + part[2] + part[3]));
}

// ---------------- f32 -> bf16 convert ----------------
__global__ __launch_bounds__(256) void k_cvt(const float* __restrict__ x, u16* __restrict__ xb, int n) {
  int i = blockIdx.x * 256 + threadIdx.x;
  if (i < n) xb[i] = f2bf(x[i]);
}

// ---------------- small GEMM: P_t[c][i] = dinv[i] * (X[i][:] . W[:][c]) ----------------
// Xs staged via gld16 with XOR-swizzled source units (16B units, f(r)=r&7) -> 2-way frag reads.
// Wt padded +8 elements -> 2-way frag reads.
__global__ __launch_bounds__(256) void k_sgemm(const u16* __restrict__ X, int kc, int lkc,
                                               const float* __restrict__ Wa, int wacols,
                                               const float* __restrict__ Wb,
                                               const float* __restrict__ dinv,
                                               u16* __restrict__ Pt) {
  __shared__ __attribute__((aligned(16))) u8 XsB[128 * 256];      // up to 128x128 bf16
  __shared__ __attribute__((aligned(16))) u16 Wt[128 * 136];      // padded stride kc+8
  int t = threadIdx.x;
  int mt = blockIdx.x;
  int ldw = kc + 8;
  for (int idx = t; idx < (kc << 7); idx += 256) {
    int n = idx >> lkc, k = idx & (kc - 1);
    float v = 0.f;
    if (n < wacols) v = Wa[k * wacols + n];
    else if (Wb)    v = Wb[k * 64 + (n - 64)];
    Wt[n * ldw + k] = f2bf(v);
  }
  const u8* gX = (const u8*)(X + (size_t)mt * 128 * kc);
  int rowbytes = kc * 2;                       // 256 or 128
  int lup = (kc == 128) ? 4 : 3;               // log2(units per row)
  int npass = (kc == 128) ? 8 : 4;
  for (int p = 0; p < npass; ++p) {
    int U = p * 256 + t;
    int row = U >> lup, lu = U & ((1 << lup) - 1);
    int g = lu ^ (row & 7);
    gld16(gX + (size_t)row * rowbytes + g * 16, XsB + (size_t)U * 16);
  }
  __syncthreads();
  int wave = t >> 6, lane = t & 63;
  int wm = (wave >> 1) * 64, wn = (wave & 1) * 64;
  int fm = lane & 15, fk = (lane >> 4) * 8;
  f4 acc[4][4];
#pragma unroll
  for (int m = 0; m < 4; ++m)
#pragma unroll
    for (int n = 0; n < 4; ++n) acc[m][n] = (f4){0.f, 0.f, 0.f, 0.f};
  for (int ki = 0; ki < kc; ki += 32) {
    frag8 a[4], b[4];
#pragma unroll
    for (int m = 0; m < 4; ++m) {
      int r = wm + 16 * m + fm;
      int gu = (ki + fk) >> 3;                 // 16B unit index
      int lu = gu ^ (r & 7);
      a[m] = *(const frag8*)&XsB[(size_t)r * rowbytes + lu * 16];
    }
#pragma unroll
    for (int n = 0; n < 4; ++n) b[n] = *(const frag8*)&Wt[(wn + 16 * n + fm) * ldw + ki + fk];
#pragma unroll
    for (int m = 0; m < 4; ++m)
#pragma unroll
      for (int n = 0; n < 4; ++n)
        acc[m][n] = __builtin_amdgcn_mfma_f32_16x16x32_bf16(a[m], b[n], acc[m][n], 0, 0, 0);
  }
  int rbase = (lane >> 4) * 4;
#pragma unroll
  for (int m = 0; m < 4; ++m) {
    int i0 = mt * 128 + wm + 16 * m + rbase;
    float d0 = dinv[i0], d1 = dinv[i0 + 1], d2 = dinv[i0 + 2], d3 = dinv[i0 + 3];
#pragma unroll
    for (int n = 0; n < 4; ++n) {
      int c = wn + 16 * n + fm;
      ushort4 o;
      o.x = f2bf(d0 * acc[m][n][0]);
      o.y = f2bf(d1 * acc[m][n][1]);
      o.z = f2bf(d2 * acc[m][n][2]);
      o.w = f2bf(d3 * acc[m][n][3]);
      *(ushort4*)&Pt[(size_t)c * N8K + i0] = o;   // P stored transposed [c][i]
    }
  }
}

// ---------------- big GEMM (split-K): Ctmp[ks] = A_hat @ P ----------------
// m97-style gld16 staging, XOR-swizzled sources: A codes (64B rows, f(r)=(r>>1)&3),
// B bf16 (128B rows, f(r)=r&7). Frag reads 2-way bank aliased = free.
__global__ __launch_bounds__(256) void k_bgemm(const u8* __restrict__ Ab,
                                               const u16* __restrict__ Pt,
                                               float* __restrict__ Ctmp) {
  __shared__ __attribute__((aligned(16))) u8 As[128 * 64];    // codes, swizzled
  __shared__ __attribute__((aligned(16))) u8 BsB[128 * 128];  // bf16 bytes, swizzled
  int t = threadIdx.x;
  int mt = blockIdx.x, ks = blockIdx.y;
  const int KS = N8K / SK;
  int wave = t >> 6, lane = t & 63;
  int wm = (wave >> 1) * 64, wn = (wave & 1) * 64;
  int fm = lane & 15, fk = (lane >> 4) * 8;
  f4 acc[4][4];
#pragma unroll
  for (int m = 0; m < 4; ++m)
#pragma unroll
    for (int n = 0; n < 4; ++n) acc[m][n] = (f4){0.f, 0.f, 0.f, 0.f};

  const u8* gA = Ab + (size_t)(mt * 128) * N8K + ks * KS;
  const u8* gB = (const u8*)Pt + (size_t)ks * KS * 2;

  for (int kk = 0; kk < KS; kk += 64) {
    __syncthreads();
#pragma unroll
    for (int p = 0; p < 2; ++p) {              // A: 128 rows x 64B, 16B units, 4/row
      int U = p * 256 + t;
      int row = U >> 2, lu = U & 3;
      int g = lu ^ ((row >> 1) & 3);
      gld16(gA + (size_t)row * N8K + kk + g * 16, As + (size_t)U * 16);
    }
#pragma unroll
    for (int p = 0; p < 4; ++p) {              // B: 128 rows x 128B, 16B units, 8/row
      int U = p * 256 + t;
      int row = U >> 3, lu = U & 7;
      int g = lu ^ (row & 7);
      gld16(gB + (size_t)row * (N8K * 2) + kk * 2 + g * 16, BsB + (size_t)U * 16);
    }
    __syncthreads();
#pragma unroll
    for (int ki = 0; ki < 64; ki += 32) {
      frag8 a[4], b[4];
#pragma unroll
      for (int m = 0; m < 4; ++m) {
        int r = wm + 16 * m + fm;
        int byo = ki + fk;                     // byte offset in 64B code row
        int gu = byo >> 4, h = (byo >> 3) & 1;
        int lu = gu ^ ((r >> 1) & 3);
        uint2 w = *(const uint2*)&As[(size_t)r * 64 + lu * 16 + h * 8];
        uint4 x;
        expand4(w.x, x.x, x.y);
        expand4(w.y, x.z, x.w);
        a[m] = *(frag8*)&x;
      }
#pragma unroll
      for (int n = 0; n < 4; ++n) {
        int r = wn + 16 * n + fm;
        int gu = (ki + fk) >> 3;               // 16B unit in 128B bf16 row
        int lu = gu ^ (r & 7);
        b[n] = *(const frag8*)&BsB[(size_t)r * 128 + lu * 16];
      }
#pragma unroll
      for (int m = 0; m < 4; ++m)
#pragma unroll
        for (int n = 0; n < 4; ++n)
          acc[m][n] = __builtin_amdgcn_mfma_f32_16x16x32_bf16(a[m], b[n], acc[m][n], 0, 0, 0);
    }
  }

  float* Co = Ctmp + (size_t)ks * N8K * 128;
  int rbase = (lane >> 4) * 4;
#pragma unroll
  for (int m = 0; m < 4; ++m) {
    int i0 = mt * 128 + wm + 16 * m + rbase;
#pragma unroll
    for (int n = 0; n < 4; ++n) {
      int c = wn + 16 * n + fm;
#pragma unroll
      for (int r = 0; r < 4; ++r) Co[(size_t)(i0 + r) * 128 + c] = acc[m][n][r];
    }
  }
}

// ---------------- epilogue: sum split-K, dinv scale, +bias, lrelu, scatter ----------------
__global__ __launch_bounds__(256) void k_epi(const float* __restrict__ Ctmp, const float* __restrict__ dinv,
                                             const float* __restrict__ bA, const float* __restrict__ bB,
                                             float* __restrict__ outF, u16* __restrict__ oB1,
                                             u16* __restrict__ oB2, int mode) {
  int idx = blockIdx.x * 256 + threadIdx.x;
  int i = idx >> 7, c = idx & 127;
  float s = 0.f;
#pragma unroll
  for (int k = 0; k < SK; ++k) s += Ctmp[(size_t)k * 1048576 + idx];
  if (mode == 1) {
    if (c < 64) oB1[i * 64 + c] = f2bf(lrelu(dinv[i] * s + bA[c]));
  } else if (mode == 2) {
    float v = lrelu(dinv[i] * s + bA[c]);
    outF[idx] = v;
    oB1[idx] = f2bf(v);
  } else if (mode == 3) {
    if (c < 64) oB1[i * 64 + c] = f2bf(lrelu(dinv[i] * s + bA[c]));
    else        oB2[i * 64 + (c - 64)] = f2bf(lrelu(dinv[i] * s + bB[c - 64]));
  } else {
    outF[idx] = lrelu(dinv[i] * s + bA[c]);
  }
}

// ---------------- recon = sigmoid(re @ re^T) ----------------
// gld16 staging with the 128B-row XOR swizzle; 2-way frag reads.
__global__ __launch_bounds__(256) void k_recon(const u16* __restrict__ re, float* __restrict__ out) {
  __shared__ __attribute__((aligned(16))) u8 RaB[128 * 128];
  __shared__ __attribute__((aligned(16))) u8 RbB[128 * 128];
  int t = threadIdx.x;
  int bi = blockIdx.x, bj = blockIdx.y;
#pragma unroll
  for (int p = 0; p < 4; ++p) {
    int U = p * 256 + t;
    int row = U >> 3, lu = U & 7;
    int g = lu ^ (row & 7);
    gld16((const u8*)re + (size_t)(bi * 128 + row) * 128 + g * 16, RaB + (size_t)U * 16);
    gld16((const u8*)re + (size_t)(bj * 128 + row) * 128 + g * 16, RbB + (size_t)U * 16);
  }
  __syncthreads();
  int wave = t >> 6, lane = t & 63;
  int wm = (wave >> 1) * 64, wn = (wave & 1) * 64;
  int fm = lane & 15, fk = (lane >> 4) * 8;
  f4 acc[4][4];
#pragma unroll
  for (int m = 0; m < 4; ++m)
#pragma unroll
    for (int n = 0; n < 4; ++n) acc[m][n] = (f4){0.f, 0.f, 0.f, 0.f};
#pragma unroll
  for (int ki = 0; ki < 64; ki += 32) {
    frag8 a[4], b[4];
#pragma unroll
    for (int m = 0; m < 4; ++m) {
      int r = wm + 16 * m + fm;
      int lu = ((ki + fk) >> 3) ^ (r & 7);
      a[m] = *(const frag8*)&RaB[(size_t)r * 128 + lu * 16];
    }
#pragma unroll
    for (int n = 0; n < 4; ++n) {
      int r = wn + 16 * n + fm;
      int lu = ((ki + fk) >> 3) ^ (r & 7);
      b[n] = *(const frag8*)&RbB[(size_t)r * 128 + lu * 16];
    }
#pragma unroll
    for (int m = 0; m < 4; ++m)
#pragma unroll
      for (int n = 0; n < 4; ++n)
        acc[m][n] = __builtin_amdgcn_mfma_f32_16x16x32_bf16(a[m], b[n], acc[m][n], 0, 0, 0);
  }
  int rbase = (lane >> 4) * 4;
#pragma unroll
  for (int m = 0; m < 4; ++m) {
#pragma unroll
    for (int n = 0; n < 4; ++n) {
      int gj = bj * 128 + wn + 16 * n + fm;
#pragma unroll
      for (int r = 0; r < 4; ++r) {
        int gi = bi * 128 + wm + 16 * m + rbase + r;
        float v = acc[m][n][r];
        out[(size_t)gi * N8K + gj] = 1.0f / (1.0f + __expf(-v));
      }
    }
  }
}

extern "C" void kernel_launch(void* const* d_in, const int* in_sizes, int n_in,
                              void* d_out, int out_size, void* d_ws, size_t ws_size,
                              hipStream_t stream) {
  const float* x   = (const float*)d_in[0];
  const int*   e   = (const int*)d_in[1];
  const float* W1  = (const float*)d_in[2];
  const float* b1  = (const float*)d_in[3];
  const float* W2  = (const float*)d_in[4];
  const float* b2  = (const float*)d_in[5];
  const float* We  = (const float*)d_in[6];
  const float* be  = (const float*)d_in[7];
  const float* Wd1 = (const float*)d_in[8];
  const float* bd1 = (const float*)d_in[9];
  const float* Wd2 = (const float*)d_in[10];
  const float* bd2 = (const float*)d_in[11];

  float* out       = (float*)d_out;
  float* out_recon = out;                         // [8192*8192]
  float* out_x     = out + 67108864;              // [8192*128]
  float* out_z     = out + 67108864 + 1048576;    // [8192*128]

  // Scratch aliased into the recon region of d_out (overwritten only by k_recon last):
  u8*    abyte = (u8*)d_out;                      // A_hat codes: 64 MB at [0,64M)
  float* Ctmp  = out + 16777216;                  // split-K partials: 32 MB at [64M,96M)

  char* ws = (char*)d_ws;
  float* dinv = (float*)(ws);
  u16* Pt   = (u16*)(ws + 32768);
  u16* xbf  = (u16*)(ws + 32768 + 2097152);
  u16* hbf  = (u16*)(ws + 32768 + 2097152 + 2097152);
  u16* zbf  = (u16*)(ws + 32768 + 2097152 + 2097152 + 1048576);
  u16* rebf = (u16*)(ws + 32768 + 2097152 + 2097152 + 1048576 + 2097152);
  u16* xdbf = (u16*)(ws + 32768 + 2097152 + 2097152 + 1048576 + 2097152 + 1048576);

  k_deg<<<8192, 256, 0, stream>>>(e, abyte, dinv);
  k_cvt<<<4096, 256, 0, stream>>>(x, xbf, 1048576);

  // stage 1: h
  k_sgemm<<<64, 256, 0, stream>>>(xbf, 128, 7, W1, 64, nullptr, dinv, Pt);
  k_bgemm<<<dim3(64, SK), 256, 0, stream>>>(abyte, Pt, Ctmp);
  k_epi<<<4096, 256, 0, stream>>>(Ctmp, dinv, b1, nullptr, nullptr, hbf, nullptr, 1);

  // stage 2: z
  k_sgemm<<<64, 256, 0, stream>>>(hbf, 64, 6, W2, 128, nullptr, dinv, Pt);
  k_bgemm<<<dim3(64, SK), 256, 0, stream>>>(abyte, Pt, Ctmp);
  k_epi<<<4096, 256, 0, stream>>>(Ctmp, dinv, b2, nullptr, out_z, zbf, nullptr, 2);

  // stage 3: [re | xd] in one GEMM via [We | Wd1]
  k_sgemm<<<64, 256, 0, stream>>>(zbf, 128, 7, We, 64, Wd1, dinv, Pt);
  k_bgemm<<<dim3(64, SK), 256, 0, stream>>>(abyte, Pt, Ctmp);
  k_epi<<<4096, 256, 0, stream>>>(Ctmp, dinv, be, bd1, nullptr, rebf, xdbf, 3);

  // stage 4: x_out
  k_sgemm<<<64, 256, 0, stream>>>(xdbf, 64, 6, Wd2, 128, nullptr, dinv, Pt);
  k_bgemm<<<dim3(64, SK), 256, 0, stream>>>(abyte, Pt, Ctmp);
  k_epi<<<4096, 256, 0, stream>>>(Ctmp, dinv, bd2, nullptr, out_x, nullptr, nullptr, 4);

  // recon = sigmoid(re @ re^T) — overwrites the abyte/Ctmp scratch region last
  k_recon<<<dim3(64, 64), 256, 0, stream>>>(rebf, out_recon);
}

// Round 5
// 686.113 us; speedup vs baseline: 1.4920x; 1.0374x over previous
//
#include <hip/hip_runtime.h>
#include <hip/hip_bf16.h>
#include <stdint.h>

typedef unsigned short u16;
typedef unsigned char u8;
typedef unsigned int u32;
typedef __attribute__((ext_vector_type(8))) short frag8;   // 8 bf16 (4 VGPRs)
typedef __attribute__((ext_vector_type(4))) float f4;      // 4 f32 acc

#define N8K 8192
#define SK 8         // split-K slices for big GEMM
#define NKT 256      // k-tiles (32 wide) across N8K

// Fragment-native ("tiled") layouts, matching mfma_f32_16x16x32_bf16 operand maps:
//   lane l <-> (row = l&15, k = (l>>4)*8 + j), unit = 8 consecutive k at fixed row.
//   X-tiled  (A-operand, [rowtile][ktile][lane][8])  : h, z, xd, re, and A_hat codes
//   B-tiled  (B-operand, [coltile][ktile][lane][8])  : Pt (k dim = node index)

__device__ __forceinline__ u16 f2bf(float f) {
  union { float f; unsigned u; } v; v.f = f;
  return (u16)((v.u + 0x7FFFu + ((v.u >> 16) & 1u)) >> 16);   // RNE
}
__device__ __forceinline__ float lrelu(float v) { return v > 0.f ? v : 0.01f * v; }

// expand 4 A-codes (bytes in w, values 0/1/2) -> 2 dwords = 4 bf16 {0,1,2}
__device__ __forceinline__ void expand4(u32 w, u32& o0, u32& o1) {
  u32 hi = __builtin_amdgcn_perm(0u, 0x00403F00u, w);
  u32 lo = __builtin_amdgcn_perm(0u, 0x00008000u, w);
  o0 = __builtin_amdgcn_perm(hi, lo, 0x05010400u);      // [lo0,hi0,lo1,hi1]
  o1 = __builtin_amdgcn_perm(hi, lo, 0x07030602u);      // [lo2,hi2,lo3,hi3]
}

// ---------------- deg: e -> A_hat codes (X-tiled bytes) + dinv ----------------
// block = one 16-row tile; thread (rl = t&15, tg = t>>4) covers k-tiles tg+16p.
__global__ __launch_bounds__(256) void k_deg(const int* __restrict__ e,
                                             u8* __restrict__ at,
                                             float* __restrict__ dinv) {
  int Rt = blockIdx.x;                     // 512 row-tiles
  int t = threadIdx.x;
  int rl = t & 15;
  int row = Rt * 16 + rl;
  int tg = t >> 4;
  int diagT = row >> 5;
  int cnt = 0;
  __shared__ int cs[256];
  for (int p = 0; p < 16; ++p) {
    int T = tg + 16 * p;
    const int4* src = (const int4*)(e + (size_t)row * N8K + T * 32);
    u32 w[8];
#pragma unroll
    for (int q8 = 0; q8 < 8; ++q8) {
      int4 v = src[q8];
      u32 c0 = (v.x != 0), c1 = (v.y != 0), c2 = (v.z != 0), c3 = (v.w != 0);
      cnt += (int)(c0 + c1 + c2 + c3);
      w[q8] = c0 | (c1 << 8) | (c2 << 16) | (c3 << 24);
    }
    if (T == diagT) {                      // self-loop on diagonal: code += 1
      int d = row & 31;
      w[d >> 2] += 1u << (8 * (d & 3));
      cnt += 1;
    }
    u8* dst = at + ((size_t)(Rt * NKT + T) * 64 + rl) * 8;
#pragma unroll
    for (int q = 0; q < 4; ++q) {          // unit q covers cols T*32 + q*8 .. +8
      uint2 u; u.x = w[2 * q]; u.y = w[2 * q + 1];
      *(uint2*)(dst + (size_t)(16 * q) * 8) = u;
    }
  }
  cs[t] = cnt;
  __syncthreads();
  if (t < 16) {
    int s = 0;
#pragma unroll
    for (int g = 0; g < 16; ++g) s += cs[t + 16 * g];
    dinv[Rt * 16 + t] = 1.0f / sqrtf((float)s);
  }
}

// ---------------- small GEMM: Pt(B-tiled) = dinv * (X @ [Wa|Wb]) ----------------
// X from X-tiled bf16 (Xt) or plain f32 (Xf, stage 1; converts in-register).
// W staged once into LDS in B-tiled form; K-loop is barrier-free.
__global__ __launch_bounds__(256, 2) void k_sgemm(const u16* __restrict__ Xt,
                                                  const float* __restrict__ Xf,
                                                  int KT,
                                                  const float* __restrict__ Wa, int wacols,
                                                  const float* __restrict__ Wb,
                                                  const float* __restrict__ dinv,
                                                  u16* __restrict__ Pt) {
  __shared__ __attribute__((aligned(16))) u16 Wt[8 * 4 * 64 * 8];   // 32 KB max (KT=4)
  int t = threadIdx.x, mt = blockIdx.x;
  int lane = t & 63, wave = t >> 6;
  int units = 8 * KT * 64;
  for (int u = t; u < units; u += 256) {
    int l = u & 63, T = (u >> 6) % KT, nt = (u >> 6) / KT;
    int n = nt * 16 + (l & 15);
    int k0 = T * 32 + (l >> 4) * 8;
    u16 tmp[8];
#pragma unroll
    for (int j = 0; j < 8; ++j) {
      int k = k0 + j;
      float v = (n < wacols) ? Wa[k * wacols + n] : (Wb ? Wb[k * 64 + (n - 64)] : 0.f);
      tmp[j] = f2bf(v);
    }
    *(uint4*)&Wt[(size_t)u * 8] = *(const uint4*)tmp;
  }
  __syncthreads();
  int wm = (wave >> 1) * 64, wn = (wave & 1) * 64;
  int fm = lane & 15, q = lane >> 4;
  f4 acc[4][4];
#pragma unroll
  for (int m = 0; m < 4; ++m)
#pragma unroll
    for (int n = 0; n < 4; ++n) acc[m][n] = (f4){0.f, 0.f, 0.f, 0.f};
  for (int T = 0; T < KT; ++T) {
    frag8 a[4], b[4];
#pragma unroll
    for (int m = 0; m < 4; ++m) {
      int Rt = mt * 8 + (wm >> 4) + m;
      if (Xf) {
        const float* px = Xf + (size_t)(Rt * 16 + fm) * (KT * 32) + T * 32 + q * 8;
        float4 v0 = *(const float4*)px, v1 = *(const float4*)(px + 4);
        u16 tmp[8] = {f2bf(v0.x), f2bf(v0.y), f2bf(v0.z), f2bf(v0.w),
                      f2bf(v1.x), f2bf(v1.y), f2bf(v1.z), f2bf(v1.w)};
        a[m] = *(const frag8*)tmp;
      } else {
        a[m] = *(const frag8*)(Xt + ((size_t)(Rt * KT + T) * 64 + lane) * 8);
      }
    }
#pragma unroll
    for (int n = 0; n < 4; ++n)
      b[n] = *(const frag8*)&Wt[((size_t)(((wn >> 4) + n) * KT + T) * 64 + lane) * 8];
#pragma unroll
    for (int m = 0; m < 4; ++m)
#pragma unroll
      for (int n = 0; n < 4; ++n)
        acc[m][n] = __builtin_amdgcn_mfma_f32_16x16x32_bf16(a[m], b[n], acc[m][n], 0, 0, 0);
  }
  // epilogue: dinv*acc -> bf16, gather 8-node units via shfl_xor(16), B-tiled store
#pragma unroll
  for (int m = 0; m < 4; ++m) {
    int ibase = mt * 128 + wm + 16 * m + q * 4;
    float d0 = dinv[ibase], d1 = dinv[ibase + 1], d2 = dinv[ibase + 2], d3 = dinv[ibase + 3];
#pragma unroll
    for (int n = 0; n < 4; ++n) {
      u32 lo = (u32)f2bf(d0 * acc[m][n][0]) | ((u32)f2bf(d1 * acc[m][n][1]) << 16);
      u32 hi = (u32)f2bf(d2 * acc[m][n][2]) | ((u32)f2bf(d3 * acc[m][n][3]) << 16);
      u32 plo = __shfl_xor(lo, 16, 64);
      u32 phi = __shfl_xor(hi, 16, 64);
      if ((q & 1) == 0) {
        uint4 u; u.x = lo; u.y = hi; u.z = plo; u.w = phi;   // nodes gi..gi+7
        int gi = mt * 128 + wm + 16 * m + (q >> 1) * 8;
        int T2 = gi >> 5;
        int lB = fm + 16 * ((gi >> 3) & 3);
        int nt = (wn >> 4) + n;
        *(uint4*)(Pt + ((size_t)(nt * NKT + T2) * 64 + lB) * 8) = u;
      }
    }
  }
}

// ---------------- big GEMM (split-K): Ctmp[ks] = A_hat @ P ----------------
// Barrier-free, LDS-free: A codes and B both in fragment-native layouts;
// every frag load is one coalesced dwordx2/x4. Compiler pipelines freely.
__global__ __launch_bounds__(256, 3) void k_bgemm(const u8* __restrict__ At,
                                                  const u16* __restrict__ Bt,
                                                  float* __restrict__ Ctmp) {
  int t = threadIdx.x;
  int mt = blockIdx.x, ks = blockIdx.y;
  int lane = t & 63, wave = t >> 6;
  int wm = (wave >> 1) * 64, wn = (wave & 1) * 64;
  f4 acc[4][4];
#pragma unroll
  for (int m = 0; m < 4; ++m)
#pragma unroll
    for (int n = 0; n < 4; ++n) acc[m][n] = (f4){0.f, 0.f, 0.f, 0.f};

  const int T0 = ks * 32;                  // 32 k-tiles per split slice
  const u8*  Ab = At + ((size_t)((mt * 8 + (wm >> 4)) * NKT + T0) * 64 + lane) * 8;
  const u16* Bb = Bt + ((size_t)(((wn >> 4)) * NKT + T0) * 64 + lane) * 8;

#pragma unroll 2
  for (int T = 0; T < 32; ++T) {
    frag8 a[4], b[4];
#pragma unroll
    for (int m = 0; m < 4; ++m) {
      uint2 w = *(const uint2*)(Ab + (size_t)m * (NKT * 512) + (size_t)T * 512);
      uint4 r;
      expand4(w.x, r.x, r.y);
      expand4(w.y, r.z, r.w);
      a[m] = *(const frag8*)&r;
    }
#pragma unroll
    for (int n = 0; n < 4; ++n)
      b[n] = *(const frag8*)(Bb + (size_t)n * (NKT * 512) + (size_t)T * 512);
#pragma unroll
    for (int m = 0; m < 4; ++m)
#pragma unroll
      for (int n = 0; n < 4; ++n)
        acc[m][n] = __builtin_amdgcn_mfma_f32_16x16x32_bf16(a[m], b[n], acc[m][n], 0, 0, 0);
  }

  float* Co = Ctmp + (size_t)ks * (N8K * 128);
  int fm = lane & 15, rbase = (lane >> 4) * 4;
#pragma unroll
  for (int m = 0; m < 4; ++m) {
    int i0 = mt * 128 + wm + 16 * m + rbase;
#pragma unroll
    for (int n = 0; n < 4; ++n) {
      int c = wn + 16 * n + fm;
#pragma unroll
      for (int r = 0; r < 4; ++r) Co[(size_t)(i0 + r) * 128 + c] = acc[m][n][r];
    }
  }
}

// ---------------- epilogue: sum split-K, dinv, +bias, lrelu, tiled scatter ----------------
// thread <-> (node i, channel octet c8); its 8 values form one tiled unit.
__global__ __launch_bounds__(256) void k_epi(const float* __restrict__ Ctmp,
                                             const float* __restrict__ dinv,
                                             const float* __restrict__ bA,
                                             const float* __restrict__ bB,
                                             float* __restrict__ outF,
                                             u16* __restrict__ o1,
                                             u16* __restrict__ o2, int mode) {
  int idx = blockIdx.x * 256 + threadIdx.x;   // 131072 = 8192 * 16
  int i = idx >> 4, c8 = idx & 15;
  if (mode == 1 && c8 >= 8) return;           // h has 64 channels
  int c0 = c8 * 8;
  float v[8];
#pragma unroll
  for (int j = 0; j < 8; ++j) v[j] = 0.f;
#pragma unroll
  for (int k = 0; k < SK; ++k) {
    const float4* p = (const float4*)(Ctmp + (size_t)k * (N8K * 128) + (size_t)i * 128 + c0);
    float4 x0 = p[0], x1 = p[1];
    v[0] += x0.x; v[1] += x0.y; v[2] += x0.z; v[3] += x0.w;
    v[4] += x1.x; v[5] += x1.y; v[6] += x1.z; v[7] += x1.w;
  }
  float di = dinv[i];
  u16 ob[8];
  if (mode == 3 && c8 >= 8) {                 // xd half, bias bB
    int cl = c0 - 64;
#pragma unroll
    for (int j = 0; j < 8; ++j) ob[j] = f2bf(lrelu(di * v[j] + bB[cl + j]));
    int T = (c8 - 8) >> 2, l = (i & 15) + 16 * ((c8 - 8) & 3);
    *(uint4*)(o2 + ((size_t)((i >> 4) * 2 + T) * 64 + l) * 8) = *(const uint4*)ob;
    return;
  }
#pragma unroll
  for (int j = 0; j < 8; ++j) v[j] = lrelu(di * v[j] + bA[c0 + j]);
  if (mode == 4) {                            // x_out plain f32
    float4* po = (float4*)(outF + (size_t)i * 128 + c0);
    po[0] = (float4){v[0], v[1], v[2], v[3]};
    po[1] = (float4){v[4], v[5], v[6], v[7]};
    return;
  }
#pragma unroll
  for (int j = 0; j < 8; ++j) ob[j] = f2bf(v[j]);
  int KTo = (mode == 2) ? 4 : 2;              // z: 128 ch; h/re: 64 ch
  int T = c8 >> 2, l = (i & 15) + 16 * (c8 & 3);
  *(uint4*)(o1 + ((size_t)((i >> 4) * KTo + T) * 64 + l) * 8) = *(const uint4*)ob;
  if (mode == 2) {                            // z also plain f32 output
    float4* po = (float4*)(outF + (size_t)i * 128 + c0);
    po[0] = (float4){v[0], v[1], v[2], v[3]};
    po[1] = (float4){v[4], v[5], v[6], v[7]};
  }
}

// ---------------- recon = sigmoid(re @ re^T) ----------------
// re is X-tiled; serves as both A and B operand. Barrier-free, LDS-free.
__global__ __launch_bounds__(256, 4) void k_recon(const u16* __restrict__ ret,
                                                  float* __restrict__ out) {
  int t = threadIdx.x;
  int bi = blockIdx.x, bj = blockIdx.y;
  int lane = t & 63, wave = t >> 6;
  int wm = (wave >> 1) * 64, wn = (wave & 1) * 64;
  int fm = lane & 15;
  f4 acc[4][4];
#pragma unroll
  for (int m = 0; m < 4; ++m)
#pragma unroll
    for (int n = 0; n < 4; ++n) acc[m][n] = (f4){0.f, 0.f, 0.f, 0.f};
#pragma unroll
  for (int T = 0; T < 2; ++T) {
    frag8 a[4], b[4];
#pragma unroll
    for (int m = 0; m < 4; ++m)
      a[m] = *(const frag8*)(ret + ((size_t)((bi * 8 + (wm >> 4) + m) * 2 + T) * 64 + lane) * 8);
#pragma unroll
    for (int n = 0; n < 4; ++n)
      b[n] = *(const frag8*)(ret + ((size_t)((bj * 8 + (wn >> 4) + n) * 2 + T) * 64 + lane) * 8);
#pragma unroll
    for (int m = 0; m < 4; ++m)
#pragma unroll
      for (int n = 0; n < 4; ++n)
        acc[m][n] = __builtin_amdgcn_mfma_f32_16x16x32_bf16(a[m], b[n], acc[m][n], 0, 0, 0);
  }
  int rbase = (lane >> 4) * 4;
#pragma unroll
  for (int m = 0; m < 4; ++m) {
#pragma unroll
    for (int n = 0; n < 4; ++n) {
      int gj = bj * 128 + wn + 16 * n + fm;
#pragma unroll
      for (int r = 0; r < 4; ++r) {
        int gi = bi * 128 + wm + 16 * m + rbase + r;
        float ex = __builtin_amdgcn_exp2f(acc[m][n][r] * -1.442695041f);
        out[(size_t)gi * N8K + gj] = __builtin_amdgcn_rcpf(1.0f + ex);
      }
    }
  }
}

extern "C" void kernel_launch(void* const* d_in, const int* in_sizes, int n_in,
                              void* d_out, int out_size, void* d_ws, size_t ws_size,
                              hipStream_t stream) {
  const float* x   = (const float*)d_in[0];
  const int*   e   = (const int*)d_in[1];
  const float* W1  = (const float*)d_in[2];
  const float* b1  = (const float*)d_in[3];
  const float* W2  = (const float*)d_in[4];
  const float* b2  = (const float*)d_in[5];
  const float* We  = (const float*)d_in[6];
  const float* be  = (const float*)d_in[7];
  const float* Wd1 = (const float*)d_in[8];
  const float* bd1 = (const float*)d_in[9];
  const float* Wd2 = (const float*)d_in[10];
  const float* bd2 = (const float*)d_in[11];

  float* out       = (float*)d_out;
  float* out_recon = out;                         // [8192*8192]
  float* out_x     = out + 67108864;              // [8192*128]
  float* out_z     = out + 67108864 + 1048576;    // [8192*128]

  // Scratch aliased into the recon region of d_out (overwritten only by k_recon last):
  u8*    at   = (u8*)d_out;                       // A_hat codes, X-tiled: 64 MB
  float* Ctmp = out + 16777216;                   // split-K partials: 32 MB

  char* ws = (char*)d_ws;                         // ~7.1 MB of d_ws
  float* dinv = (float*)(ws);
  u16* Pt  = (u16*)(ws + 32768);                  // B-tiled, 2 MB
  u16* ht  = (u16*)(ws + 32768 + 2097152);        // X-tiled, 1 MB
  u16* zt  = (u16*)(ws + 32768 + 3145728);        // X-tiled, 2 MB
  u16* ret = (u16*)(ws + 32768 + 5242880);        // X-tiled, 1 MB
  u16* xdt = (u16*)(ws + 32768 + 6291456);        // X-tiled, 1 MB

  k_deg<<<512, 256, 0, stream>>>(e, at, dinv);

  // stage 1: h = lrelu(dinv*(A_hat@(dinv*(x@W1)))+b1)  (x f32 converted in-register)
  k_sgemm<<<64, 256, 0, stream>>>(nullptr, x, 4, W1, 64, nullptr, dinv, Pt);
  k_bgemm<<<dim3(64, SK), 256, 0, stream>>>(at, Pt, Ctmp);
  k_epi<<<512, 256, 0, stream>>>(Ctmp, dinv, b1, nullptr, nullptr, ht, nullptr, 1);

  // stage 2: z
  k_sgemm<<<64, 256, 0, stream>>>(ht, nullptr, 2, W2, 128, nullptr, dinv, Pt);
  k_bgemm<<<dim3(64, SK), 256, 0, stream>>>(at, Pt, Ctmp);
  k_epi<<<512, 256, 0, stream>>>(Ctmp, dinv, b2, nullptr, out_z, zt, nullptr, 2);

  // stage 3: [re | xd] via [We | Wd1]
  k_sgemm<<<64, 256, 0, stream>>>(zt, nullptr, 4, We, 64, Wd1, dinv, Pt);
  k_bgemm<<<dim3(64, SK), 256, 0, stream>>>(at, Pt, Ctmp);
  k_epi<<<512, 256, 0, stream>>>(Ctmp, dinv, be, bd1, nullptr, ret, xdt, 3);

  // stage 4: x_out
  k_sgemm<<<64, 256, 0, stream>>>(xdt, nullptr, 2, Wd2, 128, nullptr, dinv, Pt);
  k_bgemm<<<dim3(64, SK), 256, 0, stream>>>(at, Pt, Ctmp);
  k_epi<<<512, 256, 0, stream>>>(Ctmp, dinv, bd2, nullptr, out_x, nullptr, nullptr, 4);

  // recon = sigmoid(re @ re^T) — overwrites the at/Ctmp scratch region last
  k_recon<<<dim3(64, 64), 256, 0, stream>>>(ret, out_recon);
}

// Round 7
// 683.552 us; speedup vs baseline: 1.4976x; 1.0037x over previous
//
#include <hip/hip_runtime.h>
#include <hip/hip_bf16.h>
#include <stdint.h>

typedef unsigned short u16;
typedef unsigned char u8;
typedef unsigned int u32;
typedef __attribute__((ext_vector_type(8))) short frag8;   // 8 bf16 (4 VGPRs)
typedef __attribute__((ext_vector_type(4))) float f4;      // 4 f32 acc

#define N8K 8192
#define SK 8         // split-K slices for big GEMM
#define NKT 256      // k-tiles (32 wide) across N8K

// Fragment-native ("tiled") layouts, matching mfma_f32_16x16x32_bf16 operand maps:
//   lane l <-> (row = l&15, k = (l>>4)*8 + j), unit = 8 consecutive k at fixed row.
//   X-tiled  (A-operand, [rowtile][ktile][lane][8])  : re, and A_hat codes
//   B-tiled  (B-operand, [coltile][ktile][lane][8])  : Pt (k dim = node index)

__device__ __forceinline__ u16 f2bf(float f) {
  union { float f; unsigned u; } v; v.f = f;
  return (u16)((v.u + 0x7FFFu + ((v.u >> 16) & 1u)) >> 16);   // RNE
}
__device__ __forceinline__ float lrelu(float v) { return v > 0.f ? v : 0.01f * v; }

// expand 4 A-codes (bytes in w, values 0/1/2) -> 2 dwords = 4 bf16 {0,1,2}
__device__ __forceinline__ void expand4(u32 w, u32& o0, u32& o1) {
  u32 hi = __builtin_amdgcn_perm(0u, 0x00403F00u, w);
  u32 lo = __builtin_amdgcn_perm(0u, 0x00008000u, w);
  o0 = __builtin_amdgcn_perm(hi, lo, 0x05010400u);      // [lo0,hi0,lo1,hi1]
  o1 = __builtin_amdgcn_perm(hi, lo, 0x07030602u);      // [lo2,hi2,lo3,hi3]
}

// ---------------- deg: e -> A_hat codes (X-tiled bytes) + dinv ----------------
__global__ __launch_bounds__(256) void k_deg(const int* __restrict__ e,
                                             u8* __restrict__ at,
                                             float* __restrict__ dinv) {
  int Rt = blockIdx.x;                     // 512 row-tiles
  int t = threadIdx.x;
  int rl = t & 15;
  int row = Rt * 16 + rl;
  int tg = t >> 4;
  int diagT = row >> 5;
  int cnt = 0;
  __shared__ int cs[256];
  for (int p = 0; p < 16; ++p) {
    int T = tg + 16 * p;
    const int4* src = (const int4*)(e + (size_t)row * N8K + T * 32);
    u32 w[8];
#pragma unroll
    for (int q8 = 0; q8 < 8; ++q8) {
      int4 v = src[q8];
      u32 c0 = (v.x != 0), c1 = (v.y != 0), c2 = (v.z != 0), c3 = (v.w != 0);
      cnt += (int)(c0 + c1 + c2 + c3);
      w[q8] = c0 | (c1 << 8) | (c2 << 16) | (c3 << 24);
    }
    if (T == diagT) {                      // self-loop on diagonal: code += 1
      int d = row & 31;
      w[d >> 2] += 1u << (8 * (d & 3));
      cnt += 1;
    }
    u8* dst = at + ((size_t)(Rt * NKT + T) * 64 + rl) * 8;
#pragma unroll
    for (int q = 0; q < 4; ++q) {
      uint2 u; u.x = w[2 * q]; u.y = w[2 * q + 1];
      *(uint2*)(dst + (size_t)(16 * q) * 8) = u;
    }
  }
  cs[t] = cnt;
  __syncthreads();
  if (t < 16) {
    int s = 0;
#pragma unroll
    for (int g = 0; g < 16; ++g) s += cs[t + 16 * g];
    dinv[Rt * 16 + t] = 1.0f / sqrtf((float)s);
  }
}

// ---------------- stage-1 small GEMM: Pt(B-tiled) = dinv * (x_f32 @ W1) ----------------
__global__ __launch_bounds__(256, 2) void k_sgemm1(const float* __restrict__ Xf,
                                                   const float* __restrict__ Wa,
                                                   const float* __restrict__ dinv,
                                                   u16* __restrict__ Pt) {
  const int KT = 4;
  __shared__ __attribute__((aligned(16))) u16 Wt[8 * 4 * 64 * 8];
  int t = threadIdx.x, mt = blockIdx.x;
  int lane = t & 63, wave = t >> 6;
  for (int u = t; u < 8 * KT * 64; u += 256) {
    int l = u & 63, T = (u >> 6) % KT, nt = (u >> 6) / KT;
    int n = nt * 16 + (l & 15);
    int k0 = T * 32 + (l >> 4) * 8;
    u16 tmp[8];
#pragma unroll
    for (int j = 0; j < 8; ++j) {
      int k = k0 + j;
      float v = (n < 64) ? Wa[k * 64 + n] : 0.f;
      tmp[j] = f2bf(v);
    }
    *(uint4*)&Wt[(size_t)u * 8] = *(const uint4*)tmp;
  }
  __syncthreads();
  int wm = (wave >> 1) * 64, wn = (wave & 1) * 64;
  int fm = lane & 15, q = lane >> 4;
  f4 acc[4][4];
#pragma unroll
  for (int m = 0; m < 4; ++m)
#pragma unroll
    for (int n = 0; n < 4; ++n) acc[m][n] = (f4){0.f, 0.f, 0.f, 0.f};
  for (int T = 0; T < KT; ++T) {
    frag8 a[4], b[4];
#pragma unroll
    for (int m = 0; m < 4; ++m) {
      int Rt = mt * 8 + (wm >> 4) + m;
      const float* px = Xf + (size_t)(Rt * 16 + fm) * 128 + T * 32 + q * 8;
      float4 v0 = *(const float4*)px, v1 = *(const float4*)(px + 4);
      u16 tmp[8] = {f2bf(v0.x), f2bf(v0.y), f2bf(v0.z), f2bf(v0.w),
                    f2bf(v1.x), f2bf(v1.y), f2bf(v1.z), f2bf(v1.w)};
      a[m] = *(const frag8*)tmp;
    }
#pragma unroll
    for (int n = 0; n < 4; ++n)
      b[n] = *(const frag8*)&Wt[((size_t)(((wn >> 4) + n) * KT + T) * 64 + lane) * 8];
#pragma unroll
    for (int m = 0; m < 4; ++m)
#pragma unroll
      for (int n = 0; n < 4; ++n)
        acc[m][n] = __builtin_amdgcn_mfma_f32_16x16x32_bf16(a[m], b[n], acc[m][n], 0, 0, 0);
  }
#pragma unroll
  for (int m = 0; m < 4; ++m) {
    int ibase = mt * 128 + wm + 16 * m + q * 4;
    float d0 = dinv[ibase], d1 = dinv[ibase + 1], d2 = dinv[ibase + 2], d3 = dinv[ibase + 3];
#pragma unroll
    for (int n = 0; n < 4; ++n) {
      u32 lo = (u32)f2bf(d0 * acc[m][n][0]) | ((u32)f2bf(d1 * acc[m][n][1]) << 16);
      u32 hi = (u32)f2bf(d2 * acc[m][n][2]) | ((u32)f2bf(d3 * acc[m][n][3]) << 16);
      u32 plo = __shfl_xor(lo, 16, 64);
      u32 phi = __shfl_xor(hi, 16, 64);
      if ((q & 1) == 0) {
        uint4 u; u.x = lo; u.y = hi; u.z = plo; u.w = phi;   // nodes gi..gi+7
        int gi = mt * 128 + wm + 16 * m + (q >> 1) * 8;
        int T2 = gi >> 5;
        int lB = fm + 16 * ((gi >> 3) & 3);
        int nt = (wn >> 4) + n;
        *(uint4*)(Pt + ((size_t)(nt * NKT + T2) * 64 + lB) * 8) = u;
      }
    }
  }
}

// ---------------- big GEMM (split-K): Ctmp[ks] = A_hat @ P ----------------
// Barrier-free, LDS-free: both operands fragment-native; coalesced dwordx2/x4 loads.
__global__ __launch_bounds__(256, 3) void k_bgemm(const u8* __restrict__ At,
                                                  const u16* __restrict__ Bt,
                                                  float* __restrict__ Ctmp) {
  int t = threadIdx.x;
  int mt = blockIdx.x, ks = blockIdx.y;
  int lane = t & 63, wave = t >> 6;
  int wm = (wave >> 1) * 64, wn = (wave & 1) * 64;
  f4 acc[4][4];
#pragma unroll
  for (int m = 0; m < 4; ++m)
#pragma unroll
    for (int n = 0; n < 4; ++n) acc[m][n] = (f4){0.f, 0.f, 0.f, 0.f};

  const int T0 = ks * 32;
  const u8*  Ab = At + ((size_t)((mt * 8 + (wm >> 4)) * NKT + T0) * 64 + lane) * 8;
  const u16* Bb = Bt + ((size_t)(((wn >> 4)) * NKT + T0) * 64 + lane) * 8;

#pragma unroll 2
  for (int T = 0; T < 32; ++T) {
    frag8 a[4], b[4];
#pragma unroll
    for (int m = 0; m < 4; ++m) {
      uint2 w = *(const uint2*)(Ab + (size_t)m * (NKT * 512) + (size_t)T * 512);
      uint4 r;
      expand4(w.x, r.x, r.y);
      expand4(w.y, r.z, r.w);
      a[m] = *(const frag8*)&r;
    }
#pragma unroll
    for (int n = 0; n < 4; ++n)
      b[n] = *(const frag8*)(Bb + (size_t)n * (NKT * 512) + (size_t)T * 512);
#pragma unroll
    for (int m = 0; m < 4; ++m)
#pragma unroll
      for (int n = 0; n < 4; ++n)
        acc[m][n] = __builtin_amdgcn_mfma_f32_16x16x32_bf16(a[m], b[n], acc[m][n], 0, 0, 0);
  }

  float* Co = Ctmp + (size_t)ks * (N8K * 128);
  int fm = lane & 15, rbase = (lane >> 4) * 4;
#pragma unroll
  for (int m = 0; m < 4; ++m) {
    int i0 = mt * 128 + wm + 16 * m + rbase;
#pragma unroll
    for (int n = 0; n < 4; ++n) {
      int c = wn + 16 * n + fm;
#pragma unroll
      for (int r = 0; r < 4; ++r) Co[(size_t)(i0 + r) * 128 + c] = acc[m][n][r];
    }
  }
}

// ---------------- fused epilogue_k + sgemm_{k+1} (per 128-row block) ----------------
// mode 1: epi->h (64ch, bias bE), sgemm h@W2 (KT=2)
// mode 2: epi->z (128ch, bias bE, also z f32 out), sgemm z@[We|Wd1] (KT=4)
// mode 3: epi->re (bias bE, global tiled ret) + xd (bias bE2, LDS), sgemm xd@Wd2 (KT=2)
__global__ __launch_bounds__(256, 2) void k_fuse(const float* __restrict__ Ctmp,
                                                 const float* __restrict__ dinv,
                                                 const float* __restrict__ bE,
                                                 const float* __restrict__ bE2,
                                                 float* __restrict__ outZ,
                                                 u16* __restrict__ retG,
                                                 int mode,
                                                 const float* __restrict__ Wa, int wacols,
                                                 const float* __restrict__ Wb,
                                                 u16* __restrict__ Pt) {
  __shared__ __attribute__((aligned(16))) u16 Xs[8 * 4 * 64 * 8];   // 32 KB (KT<=4)
  __shared__ __attribute__((aligned(16))) u16 Wt[8 * 4 * 64 * 8];   // 32 KB
  int t = threadIdx.x, mt = blockIdx.x;
  int lane = t & 63, wave = t >> 6;
  const int KT = (mode == 2) ? 4 : 2;      // sgemm input k-tiles

  // ---- epilogue part ----
  int C8 = (mode == 1) ? 8 : 16;           // 8-ch units per row
  int totalU = 128 * C8;
  for (int u0 = t; u0 < totalU; u0 += 256) {
    int i = (mode == 1) ? (u0 >> 3) : (u0 >> 4);
    int c8 = (mode == 1) ? (u0 & 7) : (u0 & 15);
    int gi = mt * 128 + i;
    int c0 = c8 * 8;
    float v[8];
#pragma unroll
    for (int j = 0; j < 8; ++j) v[j] = 0.f;
#pragma unroll
    for (int k = 0; k < SK; ++k) {
      const float4* p = (const float4*)(Ctmp + (size_t)k * (N8K * 128) + (size_t)gi * 128 + c0);
      float4 x0 = p[0], x1 = p[1];
      v[0] += x0.x; v[1] += x0.y; v[2] += x0.z; v[3] += x0.w;
      v[4] += x1.x; v[5] += x1.y; v[6] += x1.z; v[7] += x1.w;
    }
    float di = dinv[gi];
    u16 ob[8];
    if (mode == 3 && c8 < 8) {             // re half -> global tiled (bias bE)
#pragma unroll
      for (int j = 0; j < 8; ++j) ob[j] = f2bf(lrelu(di * v[j] + bE[c0 + j]));
      int T = c8 >> 2, l = (i & 15) + 16 * (c8 & 3);
      *(uint4*)(retG + ((size_t)((gi >> 4) * 2 + T) * 64 + l) * 8) = *(const uint4*)ob;
    } else if (mode == 3) {                // xd half -> LDS tiled (bias bE2)
      int cl = c0 - 64;
#pragma unroll
      for (int j = 0; j < 8; ++j) ob[j] = f2bf(lrelu(di * v[j] + bE2[cl + j]));
      int cp = c8 - 8;
      int T = cp >> 2, l = (i & 15) + 16 * (cp & 3);
      *(uint4*)&Xs[(((i >> 4) * 2 + T) * 64 + l) * 8] = *(const uint4*)ob;
    } else {                               // mode 1/2 -> LDS tiled (bias bE)
#pragma unroll
      for (int j = 0; j < 8; ++j) v[j] = lrelu(di * v[j] + bE[c0 + j]);
#pragma unroll
      for (int j = 0; j < 8; ++j) ob[j] = f2bf(v[j]);
      int T = c8 >> 2, l = (i & 15) + 16 * (c8 & 3);
      *(uint4*)&Xs[(((i >> 4) * KT + T) * 64 + l) * 8] = *(const uint4*)ob;
      if (mode == 2) {                     // z also plain f32 output
        float4* po = (float4*)(outZ + (size_t)gi * 128 + c0);
        po[0] = (float4){v[0], v[1], v[2], v[3]};
        po[1] = (float4){v[4], v[5], v[6], v[7]};
      }
    }
  }

  // ---- stage W into LDS (B-tiled) ----
  for (int u = t; u < 8 * KT * 64; u += 256) {
    int l = u & 63, T = (u >> 6) % KT, nt = (u >> 6) / KT;
    int n = nt * 16 + (l & 15);
    int k0 = T * 32 + (l >> 4) * 8;
    u16 tmp[8];
#pragma unroll
    for (int j = 0; j < 8; ++j) {
      int k = k0 + j;
      float v = (n < wacols) ? Wa[k * wacols + n] : (Wb ? Wb[k * 64 + (n - 64)] : 0.f);
      tmp[j] = f2bf(v);
    }
    *(uint4*)&Wt[(size_t)u * 8] = *(const uint4*)tmp;
  }
  __syncthreads();

  // ---- sgemm part: Pt = dinv * (X @ W) ----
  int wm = (wave >> 1) * 64, wn = (wave & 1) * 64;
  int fm = lane & 15, q = lane >> 4;
  f4 acc[4][4];
#pragma unroll
  for (int m = 0; m < 4; ++m)
#pragma unroll
    for (int n = 0; n < 4; ++n) acc[m][n] = (f4){0.f, 0.f, 0.f, 0.f};
  for (int T = 0; T < KT; ++T) {
    frag8 a[4], b[4];
#pragma unroll
    for (int m = 0; m < 4; ++m)
      a[m] = *(const frag8*)&Xs[((size_t)(((wm >> 4) + m) * KT + T) * 64 + lane) * 8];
#pragma unroll
    for (int n = 0; n < 4; ++n)
      b[n] = *(const frag8*)&Wt[((size_t)(((wn >> 4) + n) * KT + T) * 64 + lane) * 8];
#pragma unroll
    for (int m = 0; m < 4; ++m)
#pragma unroll
      for (int n = 0; n < 4; ++n)
        acc[m][n] = __builtin_amdgcn_mfma_f32_16x16x32_bf16(a[m], b[n], acc[m][n], 0, 0, 0);
  }
#pragma unroll
  for (int m = 0; m < 4; ++m) {
    int ibase = mt * 128 + wm + 16 * m + q * 4;
    float d0 = dinv[ibase], d1 = dinv[ibase + 1], d2 = dinv[ibase + 2], d3 = dinv[ibase + 3];
#pragma unroll
    for (int n = 0; n < 4; ++n) {
      u32 lo = (u32)f2bf(d0 * acc[m][n][0]) | ((u32)f2bf(d1 * acc[m][n][1]) << 16);
      u32 hi = (u32)f2bf(d2 * acc[m][n][2]) | ((u32)f2bf(d3 * acc[m][n][3]) << 16);
      u32 plo = __shfl_xor(lo, 16, 64);
      u32 phi = __shfl_xor(hi, 16, 64);
      if ((q & 1) == 0) {
        uint4 u; u.x = lo; u.y = hi; u.z = plo; u.w = phi;
        int gi = mt * 128 + wm + 16 * m + (q >> 1) * 8;
        int T2 = gi >> 5;
        int lB = fm + 16 * ((gi >> 3) & 3);
        int nt = (wn >> 4) + n;
        *(uint4*)(Pt + ((size_t)(nt * NKT + T2) * 64 + lB) * 8) = u;
      }
    }
  }
}

// ---------------- final epilogue: x_out = lrelu(dinv*sum + bd2) ----------------
__global__ __launch_bounds__(256) void k_epi4(const float* __restrict__ Ctmp,
                                              const float* __restrict__ dinv,
                                              const float* __restrict__ bA,
                                              float* __restrict__ outF) {
  int idx = blockIdx.x * 256 + threadIdx.x;   // 131072 = 8192 * 16
  int i = idx >> 4, c8 = idx & 15;
  int c0 = c8 * 8;
  float v[8];
#pragma unroll
  for (int j = 0; j < 8; ++j) v[j] = 0.f;
#pragma unroll
  for (int k = 0; k < SK; ++k) {
    const float4* p = (const float4*)(Ctmp + (size_t)k * (N8K * 128) + (size_t)i * 128 + c0);
    float4 x0 = p[0], x1 = p[1];
    v[0] += x0.x; v[1] += x0.y; v[2] += x0.z; v[3] += x0.w;
    v[4] += x1.x; v[5] += x1.y; v[6] += x1.z; v[7] += x1.w;
  }
  float di = dinv[i];
#pragma unroll
  for (int j = 0; j < 8; ++j) v[j] = lrelu(di * v[j] + bA[c0 + j]);
  float4* po = (float4*)(outF + (size_t)i * 128 + c0);
  po[0] = (float4){v[0], v[1], v[2], v[3]};
  po[1] = (float4){v[4], v[5], v[6], v[7]};
}

// ---------------- recon = sigmoid(re @ re^T) ----------------
__global__ __launch_bounds__(256, 4) void k_recon(const u16* __restrict__ ret,
                                                  float* __restrict__ out) {
  int t = threadIdx.x;
  int bi = blockIdx.x, bj = blockIdx.y;
  int lane = t & 63, wave = t >> 6;
  int wm = (wave >> 1) * 64, wn = (wave & 1) * 64;
  int fm = lane & 15;
  f4 acc[4][4];
#pragma unroll
  for (int m = 0; m < 4; ++m)
#pragma unroll
    for (int n = 0; n < 4; ++n) acc[m][n] = (f4){0.f, 0.f, 0.f, 0.f};
#pragma unroll
  for (int T = 0; T < 2; ++T) {
    frag8 a[4], b[4];
#pragma unroll
    for (int m = 0; m < 4; ++m)
      a[m] = *(const frag8*)(ret + ((size_t)((bi * 8 + (wm >> 4) + m) * 2 + T) * 64 + lane) * 8);
#pragma unroll
    for (int n = 0; n < 4; ++n)
      b[n] = *(const frag8*)(ret + ((size_t)((bj * 8 + (wn >> 4) + n) * 2 + T) * 64 + lane) * 8);
#pragma unroll
    for (int m = 0; m < 4; ++m)
#pragma unroll
      for (int n = 0; n < 4; ++n)
        acc[m][n] = __builtin_amdgcn_mfma_f32_16x16x32_bf16(a[m], b[n], acc[m][n], 0, 0, 0);
  }
  int rbase = (lane >> 4) * 4;
#pragma unroll
  for (int m = 0; m < 4; ++m) {
#pragma unroll
    for (int n = 0; n < 4; ++n) {
      int gj = bj * 128 + wn + 16 * n + fm;
#pragma unroll
      for (int r = 0; r < 4; ++r) {
        int gi = bi * 128 + wm + 16 * m + rbase + r;
        float ex = __builtin_amdgcn_exp2f(acc[m][n][r] * -1.442695041f);
        out[(size_t)gi * N8K + gj] = __builtin_amdgcn_rcpf(1.0f + ex);
      }
    }
  }
}

extern "C" void kernel_launch(void* const* d_in, const int* in_sizes, int n_in,
                              void* d_out, int out_size, void* d_ws, size_t ws_size,
                              hipStream_t stream) {
  const float* x   = (const float*)d_in[0];
  const int*   e   = (const int*)d_in[1];
  const float* W1  = (const float*)d_in[2];
  const float* b1  = (const float*)d_in[3];
  const float* W2  = (const float*)d_in[4];
  const float* b2  = (const float*)d_in[5];
  const float* We  = (const float*)d_in[6];
  const float* be  = (const float*)d_in[7];
  const float* Wd1 = (const float*)d_in[8];
  const float* bd1 = (const float*)d_in[9];
  const float* Wd2 = (const float*)d_in[10];
  const float* bd2 = (const float*)d_in[11];

  float* out       = (float*)d_out;
  float* out_recon = out;                         // [8192*8192]
  float* out_x     = out + 67108864;              // [8192*128]
  float* out_z     = out + 67108864 + 1048576;    // [8192*128]

  // Scratch aliased into the recon region of d_out (overwritten only by k_recon last):
  u8*    at   = (u8*)d_out;                       // A_hat codes, X-tiled: 64 MB
  float* Ctmp = out + 16777216;                   // split-K partials: 32 MB

  char* ws = (char*)d_ws;
  float* dinv = (float*)(ws);
  u16* Pt  = (u16*)(ws + 32768);                  // B-tiled, 2 MB
  u16* ret = (u16*)(ws + 32768 + 2097152);        // X-tiled re, 1 MB

  k_deg<<<512, 256, 0, stream>>>(e, at, dinv);

  // stage 1: P = dinv*(x@W1)
  k_sgemm1<<<64, 256, 0, stream>>>(x, W1, dinv, Pt);
  k_bgemm<<<dim3(64, SK), 256, 0, stream>>>(at, Pt, Ctmp);

  // epi1(h) + sgemm2(h@W2)
  k_fuse<<<64, 256, 0, stream>>>(Ctmp, dinv, b1, nullptr, nullptr, nullptr, 1,
                                 W2, 128, nullptr, Pt);
  k_bgemm<<<dim3(64, SK), 256, 0, stream>>>(at, Pt, Ctmp);

  // epi2(z; z f32 out) + sgemm3(z@[We|Wd1])
  k_fuse<<<64, 256, 0, stream>>>(Ctmp, dinv, b2, nullptr, out_z, nullptr, 2,
                                 We, 64, Wd1, Pt);
  k_bgemm<<<dim3(64, SK), 256, 0, stream>>>(at, Pt, Ctmp);

  // epi3(re -> global tiled, xd -> LDS) + sgemm4(xd@Wd2)
  k_fuse<<<64, 256, 0, stream>>>(Ctmp, dinv, be, bd1, nullptr, ret, 3,
                                 Wd2, 128, nullptr, Pt);
  k_bgemm<<<dim3(64, SK), 256, 0, stream>>>(at, Pt, Ctmp);

  // x_out
  k_epi4<<<512, 256, 0, stream>>>(Ctmp, dinv, bd2, out_x);

  // recon = sigmoid(re @ re^T) — overwrites the at/Ctmp scratch region last
  k_recon<<<dim3(64, 64), 256, 0, stream>>>(ret, out_recon);
}